// Round 2
// baseline (3447.758 us; speedup 1.0000x reference)
//
#include <hip/hip_runtime.h>

// Problem constants
#define KC    8192      // num codes
#define DD    512       // dim
#define BNR   32768     // B*N rows
#define NQ    4         // split over codes
#define QC    (KC/NQ)   // codes per quarter = 2048

// ---------------------------------------------------------------------------
// Bit-exact replication of np.sum(x*x, axis=1) for a 512-element fp32 row.
// NumPy reduce: res = x0^2 + pairwise_sum(rest 511), pairwise splits
// 511 -> 248+263 -> (120+128) + (128+(64+71)), each block the scalar
// 8-accumulator loop + fixed combine tree + sequential remainder.
// __fmul_rn/__fadd_rn forbid contraction/reassociation.
// ---------------------------------------------------------------------------
__device__ __forceinline__ float sqf(const float* p, int i) {
    return __fmul_rn(p[i], p[i]);
}

__device__ float pw_block_sq(const float* p, int off, int n) {
    float r[8];
#pragma unroll
    for (int j = 0; j < 8; j++) r[j] = sqf(p, off + j);
    int i = 8;
    const int lim = n - (n % 8);
    for (; i < lim; i += 8) {
#pragma unroll
        for (int j = 0; j < 8; j++) r[j] = __fadd_rn(r[j], sqf(p, off + i + j));
    }
    float res = __fadd_rn(
        __fadd_rn(__fadd_rn(r[0], r[1]), __fadd_rn(r[2], r[3])),
        __fadd_rn(__fadd_rn(r[4], r[5]), __fadd_rn(r[6], r[7])));
    for (; i < n; i++) res = __fadd_rn(res, sqf(p, off + i));
    return res;
}

__device__ float np_sumsq_512(const float* p) {
    const float A = pw_block_sq(p, 1, 120);     // x[1..120]
    const float B = pw_block_sq(p, 121, 128);   // x[121..248]
    const float C = pw_block_sq(p, 249, 128);   // x[249..376]
    const float D = pw_block_sq(p, 377, 64);    // x[377..440]
    const float E = pw_block_sq(p, 441, 71);    // x[441..511]
    const float s511 = __fadd_rn(__fadd_rn(A, B),
                                 __fadd_rn(C, __fadd_rn(D, E)));
    return __fadd_rn(sqf(p, 0), s511);
}

// One thread per row; consecutive threads take consecutive rows (L1 catches
// the 128B-line reuse across the sequential per-thread walk).
__global__ __launch_bounds__(64) void rowsq_kernel(const float* __restrict__ x,
                                                   float* __restrict__ out,
                                                   int nrows) {
    const int r = blockIdx.x * 64 + threadIdx.x;
    if (r < nrows) out[r] = np_sumsq_512(x + (size_t)r * DD);
}

// ---------------------------------------------------------------------------
// Fused GEMM + quantized argmin, replicating the reference fp32 rounding:
//   d[r,k] = fl32( fl32(a32[r] - 2*dot) + ce[k] ),  ties -> lowest code.
// Block: 256 threads, tile 128 rows x 128 codes, K-chunk 32, 8x8 per thread.
// ---------------------------------------------------------------------------
#define TM 128
#define TN 128
#define KB 32

__global__ __launch_bounds__(256) void argmin_kernel(
    const float* __restrict__ z, const float* __restrict__ embed,
    const float* __restrict__ ce, const float* __restrict__ a32,
    float* __restrict__ pdist, int* __restrict__ pidx) {

    __shared__ __align__(16) float As[KB][TM + 4];
    __shared__ __align__(16) float Bs[KB][TN + 4];
    __shared__ float sa[TM];

    const int tid  = threadIdx.x;
    const int tileR = blockIdx.x >> 2;       // 0..255
    const int q     = blockIdx.x & 3;        // quarter
    const int r0    = tileR * TM;
    const int cq    = q * QC;
    const int tx = tid & 15;                 // code sub-tile
    const int ty = tid >> 4;                 // row sub-tile

    if (tid < TM) sa[tid] = a32[r0 + tid];
    __syncthreads();

    float bestd[8];
    int   bestc[8];
#pragma unroll
    for (int i = 0; i < 8; i++) { bestd[i] = 3.4e38f; bestc[i] = 0; }

    for (int ct = 0; ct < QC; ct += TN) {
        const int c0 = cq + ct;
        float acc[8][8];
#pragma unroll
        for (int i = 0; i < 8; i++)
#pragma unroll
            for (int j = 0; j < 8; j++) acc[i][j] = 0.0f;

        for (int d0 = 0; d0 < DD; d0 += KB) {
#pragma unroll
            for (int l = 0; l < 4; l++) {
                const int f  = tid + 256 * l;       // 0..1023
                const int m  = f >> 3;              // 0..127
                const int k4 = (f & 7) * 4;         // 0,4,...,28
                const float4 va = *(const float4*)(z + (size_t)(r0 + m) * DD + d0 + k4);
                As[k4 + 0][m] = va.x; As[k4 + 1][m] = va.y;
                As[k4 + 2][m] = va.z; As[k4 + 3][m] = va.w;
                const float4 vb = *(const float4*)(embed + (size_t)(c0 + m) * DD + d0 + k4);
                Bs[k4 + 0][m] = vb.x; Bs[k4 + 1][m] = vb.y;
                Bs[k4 + 2][m] = vb.z; Bs[k4 + 3][m] = vb.w;
            }
            __syncthreads();

#pragma unroll
            for (int kk = 0; kk < KB; kk++) {
                float a[8], b[8];
                const float4 a0 = *(const float4*)&As[kk][ty * 8];
                const float4 a1 = *(const float4*)&As[kk][ty * 8 + 4];
                const float4 b0 = *(const float4*)&Bs[kk][tx * 8];
                const float4 b1 = *(const float4*)&Bs[kk][tx * 8 + 4];
                a[0]=a0.x; a[1]=a0.y; a[2]=a0.z; a[3]=a0.w;
                a[4]=a1.x; a[5]=a1.y; a[6]=a1.z; a[7]=a1.w;
                b[0]=b0.x; b[1]=b0.y; b[2]=b0.z; b[3]=b0.w;
                b[4]=b1.x; b[5]=b1.y; b[6]=b1.z; b[7]=b1.w;
#pragma unroll
                for (int i = 0; i < 8; i++)
#pragma unroll
                    for (int j = 0; j < 8; j++)
                        acc[i][j] = fmaf(a[i], b[j], acc[i][j]);
            }
            __syncthreads();
        }

        // Quantized fold, replicating reference rounding exactly.
#pragma unroll
        for (int j = 0; j < 8; j++) {
            const int code = c0 + tx * 8 + j;
            const float cek = ce[code];
#pragma unroll
            for (int i = 0; i < 8; i++) {
                const float t = __fsub_rn(sa[ty * 8 + i], __fmul_rn(2.0f, acc[i][j]));
                const float d = __fadd_rn(t, cek);
                if (d < bestd[i] || (d == bestd[i] && code < bestc[i])) {
                    bestd[i] = d; bestc[i] = code;
                }
            }
        }
    }

    // Block reduction: 16 tx-threads per row -> 1.  Reuse As/Bs memory.
    float* rd = (float*)&As[0][0];
    int*   ri = (int*)&Bs[0][0];
    __syncthreads();
#pragma unroll
    for (int i = 0; i < 8; i++) {
        rd[(ty * 8 + i) * 16 + tx] = bestd[i];
        ri[(ty * 8 + i) * 16 + tx] = bestc[i];
    }
    __syncthreads();
    if (tid < TM) {
        float bd = rd[tid * 16];
        int   bc = ri[tid * 16];
        for (int t = 1; t < 16; t++) {
            const float d2 = rd[tid * 16 + t];
            const int   c2 = ri[tid * 16 + t];
            if (d2 < bd || (d2 == bd && c2 < bc)) { bd = d2; bc = c2; }
        }
        pdist[(size_t)q * BNR + r0 + tid] = bd;
        pidx [(size_t)q * BNR + r0 + tid] = bc;
    }
}

// ---------------------------------------------------------------------------
// Combine quarter-winners (ties -> lowest code, matching np.argmin).
// ---------------------------------------------------------------------------
__global__ __launch_bounds__(256) void combine_kernel(
    const float* __restrict__ pdist, const int* __restrict__ pidx,
    float* __restrict__ out_codes, int* __restrict__ codes) {
    const int r = blockIdx.x * 256 + threadIdx.x;
    float bd = pdist[r];
    int   bc = pidx[r];
#pragma unroll
    for (int q = 1; q < NQ; q++) {
        const float d = pdist[(size_t)q * BNR + r];
        const int   c = pidx [(size_t)q * BNR + r];
        if (d < bd || (d == bd && c < bc)) { bd = d; bc = c; }
    }
    out_codes[r] = (float)bc;
    codes[r] = bc;
}

// ---------------------------------------------------------------------------
// z_q = embed[code] + per-row sum of (z - z_q)^2 (no atomics).
// ---------------------------------------------------------------------------
__global__ __launch_bounds__(128) void gather_loss_kernel(
    const float* __restrict__ z, const float* __restrict__ embed,
    const int* __restrict__ codes,
    float* __restrict__ out_zq, float* __restrict__ partial) {
    const int r = blockIdx.x;
    const int t = threadIdx.x;
    const int c = codes[r];
    const float4 zv = *(const float4*)(z + (size_t)r * DD + t * 4);
    const float4 ev = *(const float4*)(embed + (size_t)c * DD + t * 4);
    *(float4*)(out_zq + (size_t)r * DD + t * 4) = ev;
    const float dx = zv.x - ev.x, dy = zv.y - ev.y;
    const float dz2 = zv.z - ev.z, dw = zv.w - ev.w;
    float s = dx*dx + dy*dy + dz2*dz2 + dw*dw;
#pragma unroll
    for (int off = 32; off > 0; off >>= 1) s += __shfl_down(s, off, 64);
    __shared__ float wsum[2];
    if ((t & 63) == 0) wsum[t >> 6] = s;
    __syncthreads();
    if (t == 0) partial[r] = wsum[0] + wsum[1];
}

__global__ __launch_bounds__(256) void loss_reduce_kernel(
    const float* __restrict__ partial, float* __restrict__ out_loss) {
    const int t = threadIdx.x;
    double s = 0.0;
    for (int i = t; i < BNR; i += 256) s += (double)partial[i];
    __shared__ double sd[256];
    sd[t] = s;
    __syncthreads();
    for (int k = 128; k > 0; k >>= 1) {
        if (t < k) sd[t] += sd[t + k];
        __syncthreads();
    }
    if (t == 0) out_loss[0] = (float)(0.1 * sd[0] / (double)((size_t)BNR * DD));
}

// ---------------------------------------------------------------------------
extern "C" void kernel_launch(void* const* d_in, const int* in_sizes, int n_in,
                              void* d_out, int out_size, void* d_ws, size_t ws_size,
                              hipStream_t stream) {
    const float* z     = (const float*)d_in[0];   // (8,4096,512) f32
    const float* embed = (const float*)d_in[1];   // (8192,512)  f32
    float* out = (float*)d_out;
    float* out_zq    = out;
    float* out_codes = out + (size_t)BNR * DD;
    float* out_loss  = out + (size_t)BNR * DD + BNR;

    char* ws = (char*)d_ws;
    float* ce      = (float*)(ws + 1024);                         // 8192 f32
    float* pdist   = (float*)(ws + 65536);                        // 4*32768 f32
    int*   pidx    = (int*)  (ws + 65536 + 524288);               // 4*32768 i32
    int*   codes   = (int*)  (ws + 65536 + 2 * 524288);           // 32768 i32
    float* partial = (float*)(ws + 65536 + 2 * 524288 + 131072);  // 32768 f32
    float* a32     = (float*)(ws + 65536 + 2 * 524288 + 262144);  // 32768 f32

    rowsq_kernel<<<dim3(BNR / 64), dim3(64), 0, stream>>>(z, a32, BNR);
    rowsq_kernel<<<dim3(KC / 64), dim3(64), 0, stream>>>(embed, ce, KC);
    argmin_kernel<<<dim3((BNR / TM) * NQ), dim3(256), 0, stream>>>(z, embed, ce, a32, pdist, pidx);
    combine_kernel<<<dim3(BNR / 256), dim3(256), 0, stream>>>(pdist, pidx, out_codes, codes);
    gather_loss_kernel<<<dim3(BNR), dim3(128), 0, stream>>>(z, embed, codes, out_zq, partial);
    loss_reduce_kernel<<<dim3(1), dim3(256), 0, stream>>>(partial, out_loss);
}

// Round 3
// 2349.656 us; speedup vs baseline: 1.4673x; 1.4673x over previous
//
#include <hip/hip_runtime.h>

#define KC    8192
#define DD    512
#define BNR   32768
#define NQ    4
#define QC    (KC/NQ)

typedef _Float16 half8 __attribute__((ext_vector_type(8)));
typedef float float4v __attribute__((ext_vector_type(4)));

// ---------------------------------------------------------------------------
// np.sum(x*x, axis=1) bit-exact (from round 2, PASSED)
// ---------------------------------------------------------------------------
__device__ __forceinline__ float sqf(const float* p, int i) {
    return __fmul_rn(p[i], p[i]);
}
__device__ float pw_block_sq(const float* p, int off, int n) {
    float r[8];
#pragma unroll
    for (int j = 0; j < 8; j++) r[j] = sqf(p, off + j);
    int i = 8;
    const int lim = n - (n % 8);
    for (; i < lim; i += 8) {
#pragma unroll
        for (int j = 0; j < 8; j++) r[j] = __fadd_rn(r[j], sqf(p, off + i + j));
    }
    float res = __fadd_rn(
        __fadd_rn(__fadd_rn(r[0], r[1]), __fadd_rn(r[2], r[3])),
        __fadd_rn(__fadd_rn(r[4], r[5]), __fadd_rn(r[6], r[7])));
    for (; i < n; i++) res = __fadd_rn(res, sqf(p, off + i));
    return res;
}
__device__ float np_sumsq_512(const float* p) {
    const float A = pw_block_sq(p, 1, 120);
    const float B = pw_block_sq(p, 121, 128);
    const float C = pw_block_sq(p, 249, 128);
    const float D = pw_block_sq(p, 377, 64);
    const float E = pw_block_sq(p, 441, 71);
    const float s511 = __fadd_rn(__fadd_rn(A, B), __fadd_rn(C, __fadd_rn(D, E)));
    return __fadd_rn(sqf(p, 0), s511);
}
__global__ __launch_bounds__(64) void rowsq_kernel(const float* __restrict__ x,
                                                   float* __restrict__ out, int nrows) {
    const int r = blockIdx.x * 64 + threadIdx.x;
    if (r < nrows) out[r] = np_sumsq_512(x + (size_t)r * DD);
}

// ---------------------------------------------------------------------------
// fp16 hi/lo splits. z scale 2^11 (|z*2048| ~ up to 1.2e4 < 65504, lo normal);
// e scale 2^20 (|e*2^20| <= 128, lo normal). All cross-products scale 2^31.
// ---------------------------------------------------------------------------
__global__ __launch_bounds__(256) void split_kernel(const float* __restrict__ x,
        _Float16* __restrict__ xhi, _Float16* __restrict__ xlo,
        float scale, int* __restrict__ counter) {
    if (counter && blockIdx.x == 0 && threadIdx.x == 0) counter[0] = 0;
    const size_t i8 = ((size_t)blockIdx.x * 256 + threadIdx.x) * 8;
    const float4 v0 = *(const float4*)(x + i8);
    const float4 v1 = *(const float4*)(x + i8 + 4);
    const float s[8] = {v0.x, v0.y, v0.z, v0.w, v1.x, v1.y, v1.z, v1.w};
    half8 h, l;
#pragma unroll
    for (int j = 0; j < 8; j++) {
        const float xs = s[j] * scale;          // exact (power of 2)
        const _Float16 hh = (_Float16)xs;
        h[j] = hh;
        l[j] = (_Float16)(xs - (float)hh);      // subtraction exact
    }
    *(half8*)(xhi + i8) = h;
    *(half8*)(xlo + i8) = l;
}

// ---------------------------------------------------------------------------
// Main: fp16-split MFMA GEMM + approx best-2 argmin.
// Block 256 thr = 4 waves (2 waveRow x 2 waveCol), tile 128 rows x 128 codes,
// K-chunk 32, 64 ct-tiles... grid = 256 row-tiles x 4 code-quarters.
// d'(r,k) = ce[k] - acc*2^-30   (acc = dot * 2^31)
// LDS row stride 40 fp16 (80 B) -> b128 reads/writes spread uniformly.
// ---------------------------------------------------------------------------
__global__ __launch_bounds__(256, 2) void mfma_argmin_kernel(
    const _Float16* __restrict__ xhi, const _Float16* __restrict__ xlo,
    const _Float16* __restrict__ ehi, const _Float16* __restrict__ elo,
    const float* __restrict__ ce,
    float* __restrict__ pd1, int* __restrict__ pi1, float* __restrict__ pd2) {

    __shared__ _Float16 lds[4 * 128 * 40];
    _Float16* As_hi = lds;
    _Float16* As_lo = lds + 5120;
    _Float16* Bs_hi = lds + 10240;
    _Float16* Bs_lo = lds + 15360;

    const int tid  = threadIdx.x;
    const int tileR = blockIdx.x >> 2;
    const int q     = blockIdx.x & 3;
    const int r0    = tileR * 128;
    const int cq    = q * QC;

    const int lane = tid & 63;
    const int w    = tid >> 6;
    const int wr   = w >> 1, wc = w & 1;
    const int n16  = lane & 15, quad = lane >> 4;

    const int srow  = tid >> 1;
    const int shalf = (tid & 1) * 16;

    float bd1[16], bd2[16];
    int   bi1[16];
#pragma unroll
    for (int s = 0; s < 16; s++) { bd1[s] = 3.4e38f; bd2[s] = 3.4e38f; bi1[s] = 0; }

    const float sc = -9.31322574615478515625e-10f;   // -2^-30

    for (int ct = 0; ct < QC / 128; ct++) {
        const int c0 = cq + ct * 128;
        float4v acc[4][4];
#pragma unroll
        for (int i = 0; i < 4; i++)
#pragma unroll
            for (int j = 0; j < 4; j++) acc[i][j] = (float4v){0.f, 0.f, 0.f, 0.f};

        for (int d0 = 0; d0 < DD; d0 += 32) {
            {
                const size_t ax = (size_t)(r0 + srow) * DD + d0 + shalf;
                const size_t bx = (size_t)(c0 + srow) * DD + d0 + shalf;
                const half8 ah0 = *(const half8*)(xhi + ax);
                const half8 ah1 = *(const half8*)(xhi + ax + 8);
                const half8 al0 = *(const half8*)(xlo + ax);
                const half8 al1 = *(const half8*)(xlo + ax + 8);
                const half8 bh0 = *(const half8*)(ehi + bx);
                const half8 bh1 = *(const half8*)(ehi + bx + 8);
                const half8 bl0 = *(const half8*)(elo + bx);
                const half8 bl1 = *(const half8*)(elo + bx + 8);
                const int lo0 = srow * 40 + shalf;
                *(half8*)(As_hi + lo0) = ah0; *(half8*)(As_hi + lo0 + 8) = ah1;
                *(half8*)(As_lo + lo0) = al0; *(half8*)(As_lo + lo0 + 8) = al1;
                *(half8*)(Bs_hi + lo0) = bh0; *(half8*)(Bs_hi + lo0 + 8) = bh1;
                *(half8*)(Bs_lo + lo0) = bl0; *(half8*)(Bs_lo + lo0 + 8) = bl1;
            }
            __syncthreads();

            half8 Ah[4], Al[4];
#pragma unroll
            for (int fm = 0; fm < 4; fm++) {
                const int off = (wr * 64 + fm * 16 + n16) * 40 + quad * 8;
                Ah[fm] = *(const half8*)(As_hi + off);
                Al[fm] = *(const half8*)(As_lo + off);
            }
#pragma unroll
            for (int fn = 0; fn < 4; fn++) {
                const int off = (wc * 64 + fn * 16 + n16) * 40 + quad * 8;
                const half8 Bh = *(const half8*)(Bs_hi + off);
                const half8 Bl = *(const half8*)(Bs_lo + off);
#pragma unroll
                for (int fm = 0; fm < 4; fm++)
                    acc[fm][fn] = __builtin_amdgcn_mfma_f32_16x16x32_f16(Ah[fm], Bh, acc[fm][fn], 0, 0, 0);
#pragma unroll
                for (int fm = 0; fm < 4; fm++)
                    acc[fm][fn] = __builtin_amdgcn_mfma_f32_16x16x32_f16(Ah[fm], Bl, acc[fm][fn], 0, 0, 0);
#pragma unroll
                for (int fm = 0; fm < 4; fm++)
                    acc[fm][fn] = __builtin_amdgcn_mfma_f32_16x16x32_f16(Al[fm], Bh, acc[fm][fn], 0, 0, 0);
            }
            __syncthreads();
        }

        // fold this 128-code tile into running best-2 (codes ascend per lane)
#pragma unroll
        for (int fn = 0; fn < 4; fn++) {
            const int code = c0 + wc * 64 + fn * 16 + n16;
            const float cek = ce[code];
#pragma unroll
            for (int fm = 0; fm < 4; fm++) {
#pragma unroll
                for (int reg = 0; reg < 4; reg++) {
                    const int s = fm * 4 + reg;
                    const float d = fmaf(sc, acc[fm][fn][reg], cek);
                    if (d < bd1[s]) { bd2[s] = bd1[s]; bd1[s] = d; bi1[s] = code; }
                    else if (d <= bd2[s]) bd2[s] = d;   // d==bd1 tie lands here too
                }
            }
        }
    }

    // merge across the 16 col-lanes (butterfly over low 4 lane bits)
#pragma unroll
    for (int s = 0; s < 16; s++) {
#pragma unroll
        for (int off = 1; off < 16; off <<= 1) {
            const float od1 = __shfl_xor(bd1[s], off, 64);
            const int   oi1 = __shfl_xor(bi1[s], off, 64);
            const float od2 = __shfl_xor(bd2[s], off, 64);
            const float nd2 = fminf(fmaxf(bd1[s], od1), fminf(bd2[s], od2));
            const bool take = (od1 < bd1[s]) || (od1 == bd1[s] && oi1 < bi1[s]);
            if (take) { bd1[s] = od1; bi1[s] = oi1; }
            bd2[s] = nd2;
        }
    }

    __syncthreads();
    float* ld1 = (float*)lds;            // [2][128]
    int*   li1 = (int*)(lds + 512);
    float* ld2 = (float*)(lds + 1024);
    if (n16 == 0) {
#pragma unroll
        for (int fm = 0; fm < 4; fm++)
#pragma unroll
            for (int reg = 0; reg < 4; reg++) {
                const int s = fm * 4 + reg;
                const int rl = wr * 64 + fm * 16 + quad * 4 + reg;
                ld1[wc * 128 + rl] = bd1[s];
                li1[wc * 128 + rl] = bi1[s];
                ld2[wc * 128 + rl] = bd2[s];
            }
    }
    __syncthreads();
    if (tid < 128) {
        const float a1 = ld1[tid], b1 = ld1[128 + tid];
        const int   ai = li1[tid], bi = li1[128 + tid];
        const float a2 = ld2[tid], b2 = ld2[128 + tid];
        const float d2m = fminf(fmaxf(a1, b1), fminf(a2, b2));
        const bool take = (b1 < a1) || (b1 == a1 && bi < ai);
        pd1[(size_t)q * BNR + r0 + tid] = take ? b1 : a1;
        pi1[(size_t)q * BNR + r0 + tid] = take ? bi : ai;
        pd2[(size_t)q * BNR + r0 + tid] = d2m;
    }
}

// ---------------------------------------------------------------------------
// Combine quarters; flag rows whose top-2 gap is inside the safety band.
// band = 2*ulp(a_row [+margin]) + 1e-5  (>= 2*quantization + 4*eps_dot slack)
// ---------------------------------------------------------------------------
__global__ __launch_bounds__(256) void combine_kernel(
    const float* __restrict__ pd1, const int* __restrict__ pi1, const float* __restrict__ pd2,
    const float* __restrict__ a32, int* __restrict__ codes,
    int* __restrict__ flaglist, int* __restrict__ counter) {
    const int r = blockIdx.x * 256 + threadIdx.x;
    float d1 = pd1[r]; int i1 = pi1[r]; float d2 = pd2[r];
#pragma unroll
    for (int q = 1; q < NQ; q++) {
        const float od1 = pd1[(size_t)q * BNR + r];
        const int   oi1 = pi1[(size_t)q * BNR + r];
        const float od2 = pd2[(size_t)q * BNR + r];
        const float nd2 = fminf(fmaxf(d1, od1), fminf(d2, od2));
        const bool take = (od1 < d1) || (od1 == d1 && oi1 < i1);
        if (take) { d1 = od1; i1 = oi1; }
        d2 = nd2;
    }
    codes[r] = i1;
    const float ap = a32[r] + 1.0f;      // conservative ulp (handles +/- 2dot shift)
    const int ebits = (int)((__float_as_uint(ap) >> 23) & 255) - 127;
    const float ulpr = __uint_as_float((unsigned)(ebits - 23 + 127) << 23);
    if (d2 - d1 <= 2.0f * ulpr + 1.0e-5f) {
        const int p = atomicAdd(counter, 1);
        flaglist[p] = r;
    }
}

// ---------------------------------------------------------------------------
// Exact repair: round-2's PASSING fp32 argmin, over the flagged-row list.
// Grid fixed at worst case; blocks beyond nflag exit immediately.
// ---------------------------------------------------------------------------
#define KB 32
__global__ __launch_bounds__(256) void repair_argmin_kernel(
    const float* __restrict__ z, const float* __restrict__ embed,
    const float* __restrict__ ce, const float* __restrict__ a32,
    const int* __restrict__ flaglist, const int* __restrict__ counter,
    float* __restrict__ pdist, int* __restrict__ pidx) {

    const int nf = counter[0];
    const int tileR = blockIdx.x >> 2;
    const int r0 = tileR * 128;
    if (r0 >= nf) return;
    const int q = blockIdx.x & 3;
    const int cq = q * QC;

    __shared__ __align__(16) float As[KB][128 + 4];
    __shared__ __align__(16) float Bs[KB][128 + 4];
    __shared__ float sa[128];
    __shared__ int rowmap[128];

    const int tid = threadIdx.x;
    if (tid < 128) {
        const int p = r0 + tid;
        const int rr = flaglist[p < nf ? p : (nf - 1)];
        rowmap[tid] = rr;
        sa[tid] = a32[rr];
    }
    __syncthreads();

    const int tx = tid & 15;
    const int ty = tid >> 4;

    float bestd[8];
    int   bestc[8];
#pragma unroll
    for (int i = 0; i < 8; i++) { bestd[i] = 3.4e38f; bestc[i] = 0; }

    for (int ct = 0; ct < QC; ct += 128) {
        const int c0 = cq + ct;
        float accv[8][8];
#pragma unroll
        for (int i = 0; i < 8; i++)
#pragma unroll
            for (int j = 0; j < 8; j++) accv[i][j] = 0.0f;

        for (int d0 = 0; d0 < DD; d0 += KB) {
#pragma unroll
            for (int l = 0; l < 4; l++) {
                const int f  = tid + 256 * l;
                const int m  = f >> 3;
                const int k4 = (f & 7) * 4;
                const float4 va = *(const float4*)(z + (size_t)rowmap[m] * DD + d0 + k4);
                As[k4 + 0][m] = va.x; As[k4 + 1][m] = va.y;
                As[k4 + 2][m] = va.z; As[k4 + 3][m] = va.w;
                const float4 vb = *(const float4*)(embed + (size_t)(c0 + m) * DD + d0 + k4);
                Bs[k4 + 0][m] = vb.x; Bs[k4 + 1][m] = vb.y;
                Bs[k4 + 2][m] = vb.z; Bs[k4 + 3][m] = vb.w;
            }
            __syncthreads();
#pragma unroll
            for (int kk = 0; kk < KB; kk++) {
                float a[8], b[8];
                const float4 a0 = *(const float4*)&As[kk][ty * 8];
                const float4 a1 = *(const float4*)&As[kk][ty * 8 + 4];
                const float4 b0 = *(const float4*)&Bs[kk][tx * 8];
                const float4 b1 = *(const float4*)&Bs[kk][tx * 8 + 4];
                a[0]=a0.x; a[1]=a0.y; a[2]=a0.z; a[3]=a0.w;
                a[4]=a1.x; a[5]=a1.y; a[6]=a1.z; a[7]=a1.w;
                b[0]=b0.x; b[1]=b0.y; b[2]=b0.z; b[3]=b0.w;
                b[4]=b1.x; b[5]=b1.y; b[6]=b1.z; b[7]=b1.w;
#pragma unroll
                for (int i = 0; i < 8; i++)
#pragma unroll
                    for (int j = 0; j < 8; j++)
                        accv[i][j] = fmaf(a[i], b[j], accv[i][j]);
            }
            __syncthreads();
        }
#pragma unroll
        for (int j = 0; j < 8; j++) {
            const int code = c0 + tx * 8 + j;
            const float cek = ce[code];
#pragma unroll
            for (int i = 0; i < 8; i++) {
                const float t = __fsub_rn(sa[ty * 8 + i], __fmul_rn(2.0f, accv[i][j]));
                const float d = __fadd_rn(t, cek);
                if (d < bestd[i] || (d == bestd[i] && code < bestc[i])) {
                    bestd[i] = d; bestc[i] = code;
                }
            }
        }
    }

    float* rd = (float*)&As[0][0];
    int*   ri = (int*)&Bs[0][0];
    __syncthreads();
#pragma unroll
    for (int i = 0; i < 8; i++) {
        rd[(ty * 8 + i) * 16 + tx] = bestd[i];
        ri[(ty * 8 + i) * 16 + tx] = bestc[i];
    }
    __syncthreads();
    if (tid < 128) {
        float bd = rd[tid * 16];
        int   bc = ri[tid * 16];
        for (int t = 1; t < 16; t++) {
            const float d2 = rd[tid * 16 + t];
            const int   c2 = ri[tid * 16 + t];
            if (d2 < bd || (d2 == bd && c2 < bc)) { bd = d2; bc = c2; }
        }
        pdist[(size_t)q * BNR + r0 + tid] = bd;
        pidx [(size_t)q * BNR + r0 + tid] = bc;
    }
}

__global__ __launch_bounds__(256) void repair_combine_kernel(
    const float* __restrict__ pdist, const int* __restrict__ pidx,
    const int* __restrict__ flaglist, const int* __restrict__ counter,
    int* __restrict__ codes) {
    const int p = blockIdx.x * 256 + threadIdx.x;
    if (p >= counter[0]) return;
    float bd = pdist[p];
    int   bc = pidx[p];
#pragma unroll
    for (int q = 1; q < NQ; q++) {
        const float d = pdist[(size_t)q * BNR + p];
        const int   c = pidx [(size_t)q * BNR + p];
        if (d < bd || (d == bd && c < bc)) { bd = d; bc = c; }
    }
    codes[flaglist[p]] = bc;
}

// ---------------------------------------------------------------------------
// Epilogue: z_q gather + codes-as-float + per-row loss partial; final reduce.
// ---------------------------------------------------------------------------
__global__ __launch_bounds__(128) void gather_loss_kernel(
    const float* __restrict__ z, const float* __restrict__ embed,
    const int* __restrict__ codes,
    float* __restrict__ out_zq, float* __restrict__ out_codes,
    float* __restrict__ partial) {
    const int r = blockIdx.x;
    const int t = threadIdx.x;
    const int c = codes[r];
    const float4 zv = *(const float4*)(z + (size_t)r * DD + t * 4);
    const float4 ev = *(const float4*)(embed + (size_t)c * DD + t * 4);
    *(float4*)(out_zq + (size_t)r * DD + t * 4) = ev;
    const float dx = zv.x - ev.x, dy = zv.y - ev.y;
    const float dz2 = zv.z - ev.z, dw = zv.w - ev.w;
    float s = dx*dx + dy*dy + dz2*dz2 + dw*dw;
#pragma unroll
    for (int off = 32; off > 0; off >>= 1) s += __shfl_down(s, off, 64);
    __shared__ float wsum[2];
    if ((t & 63) == 0) wsum[t >> 6] = s;
    __syncthreads();
    if (t == 0) {
        partial[r] = wsum[0] + wsum[1];
        out_codes[r] = (float)c;
    }
}

__global__ __launch_bounds__(256) void loss_reduce_kernel(
    const float* __restrict__ partial, float* __restrict__ out_loss) {
    const int t = threadIdx.x;
    double s = 0.0;
    for (int i = t; i < BNR; i += 256) s += (double)partial[i];
    __shared__ double sd[256];
    sd[t] = s;
    __syncthreads();
    for (int k = 128; k > 0; k >>= 1) {
        if (t < k) sd[t] += sd[t + k];
        __syncthreads();
    }
    if (t == 0) out_loss[0] = (float)(0.1 * sd[0] / (double)((size_t)BNR * DD));
}

// ---------------------------------------------------------------------------
extern "C" void kernel_launch(void* const* d_in, const int* in_sizes, int n_in,
                              void* d_out, int out_size, void* d_ws, size_t ws_size,
                              hipStream_t stream) {
    const float* z     = (const float*)d_in[0];
    const float* embed = (const float*)d_in[1];
    float* out = (float*)d_out;
    float* out_zq    = out;
    float* out_codes = out + (size_t)BNR * DD;
    float* out_loss  = out + (size_t)BNR * DD + BNR;

    // z's fp16 splits live in the z_q output region (67 MB; exactly 64 MB used),
    // overwritten by gather_loss at the end.
    _Float16* xhi = (_Float16*)d_out;
    _Float16* xlo = (_Float16*)d_out + (size_t)BNR * DD;

    char* ws = (char*)d_ws;                                   // ~20 MB used
    int*   counter  = (int*)  (ws + 0);
    float* ce       = (float*)(ws + 256);
    float* a32      = (float*)(ws + 33280);
    float* pd1      = (float*)(ws + 164352);
    int*   pi1      = (int*)  (ws + 688640);
    float* pd2      = (float*)(ws + 1212928);
    float* pdist    = (float*)(ws + 1737216);
    int*   pidx     = (int*)  (ws + 2261504);
    int*   codes    = (int*)  (ws + 2785792);
    float* partial  = (float*)(ws + 2916864);
    int*   flaglist = (int*)  (ws + 3047936);
    _Float16* ehi   = (_Float16*)(ws + 3179008);
    _Float16* elo   = (_Float16*)(ws + 11567616);

    split_kernel<<<dim3(BNR * DD / (256 * 8)), dim3(256), 0, stream>>>(z, xhi, xlo, 2048.0f, counter);
    split_kernel<<<dim3(KC * DD / (256 * 8)), dim3(256), 0, stream>>>(embed, ehi, elo, 1048576.0f, (int*)nullptr);
    rowsq_kernel<<<dim3(BNR / 64), dim3(64), 0, stream>>>(z, a32, BNR);
    rowsq_kernel<<<dim3(KC / 64), dim3(64), 0, stream>>>(embed, ce, KC);
    mfma_argmin_kernel<<<dim3((BNR / 128) * NQ), dim3(256), 0, stream>>>(
        xhi, xlo, ehi, elo, ce, pd1, pi1, pd2);
    combine_kernel<<<dim3(BNR / 256), dim3(256), 0, stream>>>(
        pd1, pi1, pd2, a32, codes, flaglist, counter);
    repair_argmin_kernel<<<dim3((BNR / 128) * NQ), dim3(256), 0, stream>>>(
        z, embed, ce, a32, flaglist, counter, pdist, pidx);
    repair_combine_kernel<<<dim3(BNR / 256), dim3(256), 0, stream>>>(
        pdist, pidx, flaglist, counter, codes);
    gather_loss_kernel<<<dim3(BNR), dim3(128), 0, stream>>>(
        z, embed, codes, out_zq, out_codes, partial);
    loss_reduce_kernel<<<dim3(1), dim3(256), 0, stream>>>(partial, out_loss);
}

// Round 4
// 1487.913 us; speedup vs baseline: 2.3172x; 1.5792x over previous
//
#include <hip/hip_runtime.h>

#define KC    8192
#define DD    512
#define BNR   32768
#define NQ    4
#define QC    (KC/NQ)

typedef _Float16 half8 __attribute__((ext_vector_type(8)));
typedef float float4v __attribute__((ext_vector_type(4)));

// ---------------------------------------------------------------------------
// np.sum(x*x, axis=1) bit-exact (PASSED r2/r3)
// ---------------------------------------------------------------------------
__device__ __forceinline__ float sqf(const float* p, int i) {
    return __fmul_rn(p[i], p[i]);
}
__device__ float pw_block_sq(const float* p, int off, int n) {
    float r[8];
#pragma unroll
    for (int j = 0; j < 8; j++) r[j] = sqf(p, off + j);
    int i = 8;
    const int lim = n - (n % 8);
    for (; i < lim; i += 8) {
#pragma unroll
        for (int j = 0; j < 8; j++) r[j] = __fadd_rn(r[j], sqf(p, off + i + j));
    }
    float res = __fadd_rn(
        __fadd_rn(__fadd_rn(r[0], r[1]), __fadd_rn(r[2], r[3])),
        __fadd_rn(__fadd_rn(r[4], r[5]), __fadd_rn(r[6], r[7])));
    for (; i < n; i++) res = __fadd_rn(res, sqf(p, off + i));
    return res;
}
__device__ float np_sumsq_512(const float* p) {
    const float A = pw_block_sq(p, 1, 120);
    const float B = pw_block_sq(p, 121, 128);
    const float C = pw_block_sq(p, 249, 128);
    const float D = pw_block_sq(p, 377, 64);
    const float E = pw_block_sq(p, 441, 71);
    const float s511 = __fadd_rn(__fadd_rn(A, B), __fadd_rn(C, __fadd_rn(D, E)));
    return __fadd_rn(sqf(p, 0), s511);
}
__global__ __launch_bounds__(64) void rowsq_kernel(const float* __restrict__ x,
                                                   float* __restrict__ out, int nrows) {
    const int r = blockIdx.x * 64 + threadIdx.x;
    if (r < nrows) out[r] = np_sumsq_512(x + (size_t)r * DD);
}

// ---------------------------------------------------------------------------
// fp16 hi/lo splits (PASSED r3). z scale 2^11, e scale 2^20; products 2^31.
// ---------------------------------------------------------------------------
__global__ __launch_bounds__(256) void split_kernel(const float* __restrict__ x,
        _Float16* __restrict__ xhi, _Float16* __restrict__ xlo,
        float scale, int* __restrict__ counters) {
    if (counters && blockIdx.x == 0 && threadIdx.x == 0) { counters[0] = 0; counters[1] = 0; }
    const size_t i8 = ((size_t)blockIdx.x * 256 + threadIdx.x) * 8;
    const float4 v0 = *(const float4*)(x + i8);
    const float4 v1 = *(const float4*)(x + i8 + 4);
    const float s[8] = {v0.x, v0.y, v0.z, v0.w, v1.x, v1.y, v1.z, v1.w};
    half8 h, l;
#pragma unroll
    for (int j = 0; j < 8; j++) {
        const float xs = s[j] * scale;
        const _Float16 hh = (_Float16)xs;
        h[j] = hh;
        l[j] = (_Float16)(xs - (float)hh);
    }
    *(half8*)(xhi + i8) = h;
    *(half8*)(xlo + i8) = l;
}

// ---------------------------------------------------------------------------
// top-3 merge: (d1,i1,d2,i2,d3) <- merge with (od1,oi1,od2,oi2,od3).
// d3 needs no index; median formula for 3rd of two sorted triples.
// ---------------------------------------------------------------------------
__device__ __forceinline__ void merge3(float& d1, int& i1, float& d2, int& i2, float& d3,
                                       float od1, int oi1, float od2, int oi2, float od3) {
    const bool t1 = (od1 < d1) || (od1 == d1 && oi1 < i1);
    const float wd2 = t1 ? od2 : d2;  const int wi2 = t1 ? oi2 : i2;
    const float l1  = t1 ? d1  : od1; const int li1 = t1 ? i1  : oi1;
    const bool t2 = (l1 < wd2) || (l1 == wd2 && li1 < wi2);
    const float m1 = fmaxf(d1, od1);
    const float m2 = fminf(d2, od2);
    const float m3 = fminf(d3, od3);
    d3 = fmaxf(fminf(fmaxf(m1, m2), m3), fminf(m1, m2));   // median(m1,m2,m3)
    d2 = t2 ? l1 : wd2;  i2 = t2 ? li1 : wi2;
    d1 = t1 ? od1 : d1;  i1 = t1 ? oi1 : i1;
}

// ---------------------------------------------------------------------------
// Main: fp16-split MFMA GEMM + approx top-3 argmin, register-prefetch pipeline.
// Same LDS layout / fragment indexing as r3 (verified). Grid 256 row-tiles x 4 q.
// ---------------------------------------------------------------------------
__global__ __launch_bounds__(256, 2) void mfma_argmin_kernel(
    const _Float16* __restrict__ xhi, const _Float16* __restrict__ xlo,
    const _Float16* __restrict__ ehi, const _Float16* __restrict__ elo,
    const float* __restrict__ ce,
    float* __restrict__ pd1, int* __restrict__ pi1,
    float* __restrict__ pd2, int* __restrict__ pi2, float* __restrict__ pd3) {

    __shared__ _Float16 lds[4 * 128 * 40];
    _Float16* As_hi = lds;
    _Float16* As_lo = lds + 5120;
    _Float16* Bs_hi = lds + 10240;
    _Float16* Bs_lo = lds + 15360;

    const int tid  = threadIdx.x;
    const int tileR = blockIdx.x >> 2;
    const int q     = blockIdx.x & 3;
    const int r0    = tileR * 128;
    const int cq    = q * QC;

    const int lane = tid & 63;
    const int w    = tid >> 6;
    const int wr   = w >> 1, wc = w & 1;
    const int n16  = lane & 15, quad = lane >> 4;

    const int srow  = tid >> 1;
    const int shalf = (tid & 1) * 16;
    const int lo0   = srow * 40 + shalf;

    float bd1[16], bd2[16], bd3[16];
    int   bi1[16], bi2[16];
#pragma unroll
    for (int s = 0; s < 16; s++) {
        bd1[s] = 3.4e38f; bd2[s] = 3.4e38f; bd3[s] = 3.4e38f;
        bi1[s] = 0; bi2[s] = 0;
    }

    const float sc = -9.31322574615478515625e-10f;   // -2^-30

    const size_t aIdx = (size_t)(r0 + srow) * DD + shalf;

    // prologue: prefetch (ct=0, d0=0)
    half8 pah0 = *(const half8*)(xhi + aIdx);
    half8 pah1 = *(const half8*)(xhi + aIdx + 8);
    half8 pal0 = *(const half8*)(xlo + aIdx);
    half8 pal1 = *(const half8*)(xlo + aIdx + 8);
    size_t bIdx0 = (size_t)(cq + srow) * DD + shalf;
    half8 pbh0 = *(const half8*)(ehi + bIdx0);
    half8 pbh1 = *(const half8*)(ehi + bIdx0 + 8);
    half8 pbl0 = *(const half8*)(elo + bIdx0);
    half8 pbl1 = *(const half8*)(elo + bIdx0 + 8);

    for (int ct = 0; ct < 16; ct++) {
        const int c0 = cq + ct * 128;
        float4v acc[4][4];
#pragma unroll
        for (int i = 0; i < 4; i++)
#pragma unroll
            for (int j = 0; j < 4; j++) acc[i][j] = (float4v){0.f, 0.f, 0.f, 0.f};

        for (int d0i = 0; d0i < 16; d0i++) {
            __syncthreads();                       // everyone done reading LDS
            *(half8*)(As_hi + lo0) = pah0; *(half8*)(As_hi + lo0 + 8) = pah1;
            *(half8*)(As_lo + lo0) = pal0; *(half8*)(As_lo + lo0 + 8) = pal1;
            *(half8*)(Bs_hi + lo0) = pbh0; *(half8*)(Bs_hi + lo0 + 8) = pbh1;
            *(half8*)(Bs_lo + lo0) = pbl0; *(half8*)(Bs_lo + lo0 + 8) = pbl1;
            __syncthreads();

            // prefetch next iteration (overlaps the MFMA block below)
            const int nit = ct * 16 + d0i + 1;
            if (nit < 256) {
                const int nct = nit >> 4;
                const int nd0 = (nit & 15) * 32;
                const size_t ai = aIdx + nd0;
                pah0 = *(const half8*)(xhi + ai); pah1 = *(const half8*)(xhi + ai + 8);
                pal0 = *(const half8*)(xlo + ai); pal1 = *(const half8*)(xlo + ai + 8);
                const size_t bi = (size_t)(cq + nct * 128 + srow) * DD + shalf + nd0;
                pbh0 = *(const half8*)(ehi + bi); pbh1 = *(const half8*)(ehi + bi + 8);
                pbl0 = *(const half8*)(elo + bi); pbl1 = *(const half8*)(elo + bi + 8);
            }

            half8 Ah[4], Al[4];
#pragma unroll
            for (int fm = 0; fm < 4; fm++) {
                const int off = (wr * 64 + fm * 16 + n16) * 40 + quad * 8;
                Ah[fm] = *(const half8*)(As_hi + off);
                Al[fm] = *(const half8*)(As_lo + off);
            }
#pragma unroll
            for (int fn = 0; fn < 4; fn++) {
                const int off = (wc * 64 + fn * 16 + n16) * 40 + quad * 8;
                const half8 Bh = *(const half8*)(Bs_hi + off);
                const half8 Bl = *(const half8*)(Bs_lo + off);
#pragma unroll
                for (int fm = 0; fm < 4; fm++)
                    acc[fm][fn] = __builtin_amdgcn_mfma_f32_16x16x32_f16(Ah[fm], Bh, acc[fm][fn], 0, 0, 0);
#pragma unroll
                for (int fm = 0; fm < 4; fm++)
                    acc[fm][fn] = __builtin_amdgcn_mfma_f32_16x16x32_f16(Ah[fm], Bl, acc[fm][fn], 0, 0, 0);
#pragma unroll
                for (int fm = 0; fm < 4; fm++)
                    acc[fm][fn] = __builtin_amdgcn_mfma_f32_16x16x32_f16(Al[fm], Bh, acc[fm][fn], 0, 0, 0);
            }
        }

        // fold into per-slot top-3 (codes ascend per slot over ct)
#pragma unroll
        for (int fn = 0; fn < 4; fn++) {
            const int code = c0 + wc * 64 + fn * 16 + n16;
            const float cek = ce[code];
#pragma unroll
            for (int fm = 0; fm < 4; fm++) {
#pragma unroll
                for (int reg = 0; reg < 4; reg++) {
                    const int s = fm * 4 + reg;
                    const float d = fmaf(sc, acc[fm][fn][reg], cek);
                    const bool lt1 = d < bd1[s];
                    const bool lt2 = d < bd2[s];
                    const bool lt3 = d < bd3[s];
                    bd3[s] = lt2 ? bd2[s] : (lt3 ? d : bd3[s]);
                    bd2[s] = lt1 ? bd1[s] : (lt2 ? d : bd2[s]);
                    bi2[s] = lt1 ? bi1[s] : (lt2 ? code : bi2[s]);
                    bd1[s] = lt1 ? d : bd1[s];
                    bi1[s] = lt1 ? code : bi1[s];
                }
            }
        }
    }

    // butterfly merge across the 16 col-lanes
#pragma unroll
    for (int s = 0; s < 16; s++) {
#pragma unroll
        for (int off = 1; off < 16; off <<= 1) {
            const float od1 = __shfl_xor(bd1[s], off, 64);
            const int   oi1 = __shfl_xor(bi1[s], off, 64);
            const float od2 = __shfl_xor(bd2[s], off, 64);
            const int   oi2 = __shfl_xor(bi2[s], off, 64);
            const float od3 = __shfl_xor(bd3[s], off, 64);
            merge3(bd1[s], bi1[s], bd2[s], bi2[s], bd3[s], od1, oi1, od2, oi2, od3);
        }
    }

    __syncthreads();
    float* ld1 = (float*)lds;            // [2][128] each
    int*   li1 = (int*)(lds + 1024 * 1);
    float* ld2 = (float*)(lds + 1024 * 2);
    int*   li2 = (int*)(lds + 1024 * 3);
    float* ld3 = (float*)(lds + 1024 * 4);
    if (n16 == 0) {
#pragma unroll
        for (int fm = 0; fm < 4; fm++)
#pragma unroll
            for (int reg = 0; reg < 4; reg++) {
                const int s = fm * 4 + reg;
                const int rl = wr * 64 + fm * 16 + quad * 4 + reg;
                ld1[wc * 128 + rl] = bd1[s];
                li1[wc * 128 + rl] = bi1[s];
                ld2[wc * 128 + rl] = bd2[s];
                li2[wc * 128 + rl] = bi2[s];
                ld3[wc * 128 + rl] = bd3[s];
            }
    }
    __syncthreads();
    if (tid < 128) {
        float d1 = ld1[tid]; int i1 = li1[tid];
        float d2 = ld2[tid]; int i2 = li2[tid];
        float d3 = ld3[tid];
        merge3(d1, i1, d2, i2, d3,
               ld1[128 + tid], li1[128 + tid], ld2[128 + tid], li2[128 + tid], ld3[128 + tid]);
        const size_t o = (size_t)q * BNR + r0 + tid;
        pd1[o] = d1; pi1[o] = i1; pd2[o] = d2; pi2[o] = i2; pd3[o] = d3;
    }
}

// ---------------------------------------------------------------------------
// Combine quarters; classify rows: clean / pair-repair / full-repair.
// band = 2*ulp(a+1) + 1e-5 (same as r3, validated).
// ---------------------------------------------------------------------------
__global__ __launch_bounds__(256) void combine_kernel(
    const float* __restrict__ pd1, const int* __restrict__ pi1,
    const float* __restrict__ pd2, const int* __restrict__ pi2,
    const float* __restrict__ pd3,
    const float* __restrict__ a32, int* __restrict__ codes,
    int* __restrict__ pairlist, int* __restrict__ fulllist,
    unsigned long long* __restrict__ fkey, int* __restrict__ counters) {
    const int r = blockIdx.x * 256 + threadIdx.x;
    float d1 = pd1[r]; int i1 = pi1[r];
    float d2 = pd2[r]; int i2 = pi2[r];
    float d3 = pd3[r];
#pragma unroll
    for (int q = 1; q < NQ; q++) {
        const size_t o = (size_t)q * BNR + r;
        merge3(d1, i1, d2, i2, d3, pd1[o], pi1[o], pd2[o], pi2[o], pd3[o]);
    }
    codes[r] = i1;                      // provisional (correct for clean rows)
    const float ap = a32[r] + 1.0f;
    const int ebits = (int)((__float_as_uint(ap) >> 23) & 255) - 127;
    const float ulpr = __uint_as_float((unsigned)(ebits - 23 + 127) << 23);
    const float band = 2.0f * ulpr + 1.0e-5f;
    if (d2 - d1 <= band) {
        if (d3 - d1 > band) {
            const int p = atomicAdd(&counters[0], 1);
            pairlist[2 * p]     = r;
            pairlist[2 * p + 1] = i1 | (i2 << 13);
        } else {
            const int p = atomicAdd(&counters[1], 1);
            fulllist[p] = r;
            fkey[p] = 0xFFFFFFFFFFFFFFFFULL;
        }
    }
}

// ---------------------------------------------------------------------------
// Pair repair: exact quantized compare of the only two possible winners.
// One wave per flagged row.
// ---------------------------------------------------------------------------
__global__ __launch_bounds__(256) void pair_repair_kernel(
    const float* __restrict__ z, const float* __restrict__ embed,
    const float* __restrict__ ce, const float* __restrict__ a32,
    const int* __restrict__ pairlist, const int* __restrict__ counters,
    int* __restrict__ codes) {
    const int p = blockIdx.x * 4 + (threadIdx.x >> 6);
    if (p >= counters[0]) return;
    const int r  = pairlist[2 * p];
    const int pc = pairlist[2 * p + 1];
    const int c1 = pc & 8191, c2 = (pc >> 13) & 8191;
    const int lane = threadIdx.x & 63;
    const float* zr = z + (size_t)r * DD + lane * 8;
    const float* e1 = embed + (size_t)c1 * DD + lane * 8;
    const float* e2 = embed + (size_t)c2 * DD + lane * 8;
    const float4 x0 = *(const float4*)zr,        x1 = *(const float4*)(zr + 4);
    const float4 a0 = *(const float4*)e1,        a1 = *(const float4*)(e1 + 4);
    const float4 b0 = *(const float4*)e2,        b1 = *(const float4*)(e2 + 4);
    float s1 = x0.x*a0.x + x0.y*a0.y + x0.z*a0.z + x0.w*a0.w
             + x1.x*a1.x + x1.y*a1.y + x1.z*a1.z + x1.w*a1.w;
    float s2 = x0.x*b0.x + x0.y*b0.y + x0.z*b0.z + x0.w*b0.w
             + x1.x*b1.x + x1.y*b1.y + x1.z*b1.z + x1.w*b1.w;
#pragma unroll
    for (int off = 32; off > 0; off >>= 1) {
        s1 += __shfl_down(s1, off, 64);
        s2 += __shfl_down(s2, off, 64);
    }
    if (lane == 0) {
        const float ar = a32[r];
        const float dq1 = __fadd_rn(__fsub_rn(ar, __fmul_rn(2.0f, s1)), ce[c1]);
        const float dq2 = __fadd_rn(__fsub_rn(ar, __fmul_rn(2.0f, s2)), ce[c2]);
        const bool t = (dq2 < dq1) || (dq2 == dq1 && c2 < c1);
        codes[r] = t ? c2 : c1;
    }
}

// ---------------------------------------------------------------------------
// Full repair v2: row-parallel. Block = (row-slot, 1/8 code chunk); each wave
// scans 256 codes with full-row fp32 dot; block winners -> atomicMin(u64 key).
// ---------------------------------------------------------------------------
__global__ __launch_bounds__(256) void full_repair_kernel(
    const float* __restrict__ z, const float* __restrict__ embed,
    const float* __restrict__ ce, const float* __restrict__ a32,
    const int* __restrict__ fulllist, const int* __restrict__ counters,
    unsigned long long* __restrict__ fkey) {
    const int nf = counters[1];
    const int chunk = blockIdx.x & 7;
    const int lane = threadIdx.x & 63;
    const int wv = threadIdx.x >> 6;
    __shared__ float xs[512];
    for (int slot = blockIdx.x >> 3; slot < nf; slot += 2048) {
        const int r = fulllist[slot];
        __syncthreads();
        if (threadIdx.x < 128)
            ((float4*)xs)[threadIdx.x] = ((const float4*)(z + (size_t)r * DD))[threadIdx.x];
        __syncthreads();
        float x[8];
        *(float4*)&x[0] = ((float4*)xs)[lane * 2];
        *(float4*)&x[4] = ((float4*)xs)[lane * 2 + 1];
        const float ar = a32[r];
        float bd = 3.4e38f; int bc = 0x7fffffff;
        const int cbase = chunk * 1024 + wv * 256;
        for (int cc = 0; cc < 256; cc++) {
            const int c = cbase + cc;
            const float* er = embed + (size_t)c * DD + lane * 8;
            const float4 e0 = *(const float4*)er, e1 = *(const float4*)(er + 4);
            float s = x[0]*e0.x + x[1]*e0.y + x[2]*e0.z + x[3]*e0.w
                    + x[4]*e1.x + x[5]*e1.y + x[6]*e1.z + x[7]*e1.w;
#pragma unroll
            for (int off = 32; off > 0; off >>= 1) s += __shfl_down(s, off, 64);
            s = __shfl(s, 0, 64);
            const float dq = __fadd_rn(__fsub_rn(ar, __fmul_rn(2.0f, s)), ce[c]);
            if (dq < bd || (dq == bd && c < bc)) { bd = dq; bc = c; }
        }
        if (lane == 0) {
            unsigned int fb = __float_as_uint(bd);
            fb = (fb & 0x80000000u) ? ~fb : (fb | 0x80000000u);
            const unsigned long long key = ((unsigned long long)fb << 32) | (unsigned)bc;
            atomicMin(&fkey[slot], key);
        }
    }
}

__global__ __launch_bounds__(256) void full_combine_kernel(
    const unsigned long long* __restrict__ fkey, const int* __restrict__ fulllist,
    const int* __restrict__ counters, int* __restrict__ codes) {
    const int nf = counters[1];
    for (int p = blockIdx.x * 256 + threadIdx.x; p < nf; p += 32768)
        codes[fulllist[p]] = (int)(fkey[p] & 0xFFFFFFFFULL);
}

// ---------------------------------------------------------------------------
// Epilogue: z_q gather + codes-as-float + per-row loss partial; final reduce.
// ---------------------------------------------------------------------------
__global__ __launch_bounds__(128) void gather_loss_kernel(
    const float* __restrict__ z, const float* __restrict__ embed,
    const int* __restrict__ codes,
    float* __restrict__ out_zq, float* __restrict__ out_codes,
    float* __restrict__ partial) {
    const int r = blockIdx.x;
    const int t = threadIdx.x;
    const int c = codes[r];
    const float4 zv = *(const float4*)(z + (size_t)r * DD + t * 4);
    const float4 ev = *(const float4*)(embed + (size_t)c * DD + t * 4);
    *(float4*)(out_zq + (size_t)r * DD + t * 4) = ev;
    const float dx = zv.x - ev.x, dy = zv.y - ev.y;
    const float dz2 = zv.z - ev.z, dw = zv.w - ev.w;
    float s = dx*dx + dy*dy + dz2*dz2 + dw*dw;
#pragma unroll
    for (int off = 32; off > 0; off >>= 1) s += __shfl_down(s, off, 64);
    __shared__ float wsum[2];
    if ((t & 63) == 0) wsum[t >> 6] = s;
    __syncthreads();
    if (t == 0) {
        partial[r] = wsum[0] + wsum[1];
        out_codes[r] = (float)c;
    }
}

__global__ __launch_bounds__(256) void loss_reduce_kernel(
    const float* __restrict__ partial, float* __restrict__ out_loss) {
    const int t = threadIdx.x;
    double s = 0.0;
    for (int i = t; i < BNR; i += 256) s += (double)partial[i];
    __shared__ double sd[256];
    sd[t] = s;
    __syncthreads();
    for (int k = 128; k > 0; k >>= 1) {
        if (t < k) sd[t] += sd[t + k];
        __syncthreads();
    }
    if (t == 0) out_loss[0] = (float)(0.1 * sd[0] / (double)((size_t)BNR * DD));
}

// ---------------------------------------------------------------------------
extern "C" void kernel_launch(void* const* d_in, const int* in_sizes, int n_in,
                              void* d_out, int out_size, void* d_ws, size_t ws_size,
                              hipStream_t stream) {
    const float* z     = (const float*)d_in[0];
    const float* embed = (const float*)d_in[1];
    float* out = (float*)d_out;
    float* out_zq    = out;
    float* out_codes = out + (size_t)BNR * DD;
    float* out_loss  = out + (size_t)BNR * DD + BNR;

    // z's fp16 splits live in the z_q output region (overwritten at the end).
    _Float16* xhi = (_Float16*)d_out;
    _Float16* xlo = (_Float16*)d_out + (size_t)BNR * DD;

    char* ws = (char*)d_ws;
    int*   counters = (int*)  (ws + 0);          // 2 ints
    float* ce       = (float*)(ws + 256);        // 32 KB -> 33024
    float* a32      = (float*)(ws + 33024);      // 128 KB -> 164096
    float* pd1      = (float*)(ws + 164096);     // 512 KB -> 688384
    int*   pi1      = (int*)  (ws + 688384);     // 512 KB -> 1212672
    float* pd2      = (float*)(ws + 1212672);    // 512 KB -> 1736960
    int*   pi2      = (int*)  (ws + 1736960);    // 512 KB -> 2261248
    float* pd3      = (float*)(ws + 2261248);    // 512 KB -> 2785536
    int*   codes    = (int*)  (ws + 2785536);    // 128 KB -> 2916608
    int*   pairlist = (int*)  (ws + 2916608);    // 256 KB -> 3178752
    int*   fulllist = (int*)  (ws + 3178752);    // 128 KB -> 3309824
    unsigned long long* fkey = (unsigned long long*)(ws + 3309824); // 256 KB -> 3571968
    _Float16* ehi   = (_Float16*)(ws + 3571968); // 8 MB -> 11960576
    _Float16* elo   = (_Float16*)(ws + 11960576);// 8 MB -> 20349184
    float* partial  = pd1;                       // overlay: pd1 dead after combine

    split_kernel<<<dim3(BNR * DD / (256 * 8)), dim3(256), 0, stream>>>(z, xhi, xlo, 2048.0f, counters);
    split_kernel<<<dim3(KC * DD / (256 * 8)), dim3(256), 0, stream>>>(embed, ehi, elo, 1048576.0f, (int*)nullptr);
    rowsq_kernel<<<dim3(BNR / 64), dim3(64), 0, stream>>>(z, a32, BNR);
    rowsq_kernel<<<dim3(KC / 64), dim3(64), 0, stream>>>(embed, ce, KC);
    mfma_argmin_kernel<<<dim3((BNR / 128) * NQ), dim3(256), 0, stream>>>(
        xhi, xlo, ehi, elo, ce, pd1, pi1, pd2, pi2, pd3);
    combine_kernel<<<dim3(BNR / 256), dim3(256), 0, stream>>>(
        pd1, pi1, pd2, pi2, pd3, a32, codes, pairlist, fulllist, fkey, counters);
    pair_repair_kernel<<<dim3(8192), dim3(256), 0, stream>>>(
        z, embed, ce, a32, pairlist, counters, codes);
    full_repair_kernel<<<dim3(16384), dim3(256), 0, stream>>>(
        z, embed, ce, a32, fulllist, counters, fkey);
    full_combine_kernel<<<dim3(128), dim3(256), 0, stream>>>(
        fkey, fulllist, counters, codes);
    gather_loss_kernel<<<dim3(BNR), dim3(128), 0, stream>>>(
        z, embed, codes, out_zq, out_codes, partial);
    loss_reduce_kernel<<<dim3(1), dim3(256), 0, stream>>>(partial, out_loss);
}

// Round 5
// 1310.245 us; speedup vs baseline: 2.6314x; 1.1356x over previous
//
#include <hip/hip_runtime.h>

#define KC    8192
#define DD    512
#define BNR   32768
#define NQ    4
#define QC    (KC/NQ)

typedef _Float16 half8 __attribute__((ext_vector_type(8)));
typedef float float4v __attribute__((ext_vector_type(4)));

// ---------------------------------------------------------------------------
// sq helper (exact, no contraction)
// ---------------------------------------------------------------------------
__device__ __forceinline__ float sqf(const float* p, int i) {
    return __fmul_rn(p[i], p[i]);
}

// ---------------------------------------------------------------------------
// Wave-per-row np.sum(x*x, axis=1), bit-exact vs NumPy pairwise reduce:
// res = x0^2 + [(A+B)+(C+(D+E))], blocks A(1,120) B(121,128) C(249,128)
// D(377,64) E(441,71). Within a block: 8 accumulators r[j] (lane j of the
// 8-lane group), combine ((r0+r1)+(r2+r3))+((r4+r5)+(r6+r7)) via shfl_xor
// (commutative adds -> identical rounding), E remainder sequential.
// ---------------------------------------------------------------------------
__global__ __launch_bounds__(256) void rowsq_wave_kernel(const float* __restrict__ x,
                                                         float* __restrict__ out, int nrows) {
    const int wid = (int)((blockIdx.x * 256 + threadIdx.x) >> 6);
    if (wid >= nrows) return;                 // wave-uniform
    const int lane = threadIdx.x & 63;
    const float* p = x + (size_t)wid * DD;
    const int g = lane >> 3, j = lane & 7;
    const int offs[8] = {1, 121, 249, 377, 441, 0, 0, 0};
    const int its[8]  = {15, 16, 16, 8, 8, 0, 0, 0};
    float r = 0.0f;
    if (g < 5) {
        const int off = offs[g], n = its[g];
        r = sqf(p, off + j);
        for (int i = 1; i < n; i++) r = __fadd_rn(r, sqf(p, off + 8 * i + j));
    }
    r = __fadd_rn(r, __shfl_xor(r, 1, 64));
    r = __fadd_rn(r, __shfl_xor(r, 2, 64));
    r = __fadd_rn(r, __shfl_xor(r, 4, 64));
    float e = r;
    if (lane == 32) {                          // E remainder: x[505..511]
        for (int k = 0; k < 7; k++) e = __fadd_rn(e, sqf(p, 505 + k));
    }
    const float A = __shfl(r, 0, 64);
    const float B = __shfl(r, 8, 64);
    const float C = __shfl(r, 16, 64);
    const float Dv = __shfl(r, 24, 64);
    const float E = __shfl(e, 32, 64);
    if (lane == 0) {
        const float s511 = __fadd_rn(__fadd_rn(A, B), __fadd_rn(C, __fadd_rn(Dv, E)));
        out[wid] = __fadd_rn(sqf(p, 0), s511);
    }
}

// ---------------------------------------------------------------------------
// Splits. z: hi only (scale 2^11). e: hi+lo (scale 2^20). Kept products
// x_hi*e_hi and x_hi*e_lo share the 2^31 scale.
// ---------------------------------------------------------------------------
__global__ __launch_bounds__(256) void split_hi_kernel(const float* __restrict__ x,
        _Float16* __restrict__ xhi, float scale, int* __restrict__ counters) {
    if (counters && blockIdx.x == 0 && threadIdx.x == 0) { counters[0] = 0; counters[1] = 0; }
    const size_t i8 = ((size_t)blockIdx.x * 256 + threadIdx.x) * 8;
    const float4 v0 = *(const float4*)(x + i8);
    const float4 v1 = *(const float4*)(x + i8 + 4);
    const float s[8] = {v0.x, v0.y, v0.z, v0.w, v1.x, v1.y, v1.z, v1.w};
    half8 h;
#pragma unroll
    for (int j = 0; j < 8; j++) h[j] = (_Float16)(s[j] * scale);
    *(half8*)(xhi + i8) = h;
}

__global__ __launch_bounds__(256) void split_hilo_kernel(const float* __restrict__ x,
        _Float16* __restrict__ xhi, _Float16* __restrict__ xlo, float scale) {
    const size_t i8 = ((size_t)blockIdx.x * 256 + threadIdx.x) * 8;
    const float4 v0 = *(const float4*)(x + i8);
    const float4 v1 = *(const float4*)(x + i8 + 4);
    const float s[8] = {v0.x, v0.y, v0.z, v0.w, v1.x, v1.y, v1.z, v1.w};
    half8 h, l;
#pragma unroll
    for (int j = 0; j < 8; j++) {
        const float xs = s[j] * scale;
        const _Float16 hh = (_Float16)xs;
        h[j] = hh;
        l[j] = (_Float16)(xs - (float)hh);
    }
    *(half8*)(xhi + i8) = h;
    *(half8*)(xlo + i8) = l;
}

// ---------------------------------------------------------------------------
// top-3 merge (r4, validated)
// ---------------------------------------------------------------------------
__device__ __forceinline__ void merge3(float& d1, int& i1, float& d2, int& i2, float& d3,
                                       float od1, int oi1, float od2, int oi2, float od3) {
    const bool t1 = (od1 < d1) || (od1 == d1 && oi1 < i1);
    const float wd2 = t1 ? od2 : d2;  const int wi2 = t1 ? oi2 : i2;
    const float l1  = t1 ? d1  : od1; const int li1 = t1 ? i1  : oi1;
    const bool t2 = (l1 < wd2) || (l1 == wd2 && li1 < wi2);
    const float m1 = fmaxf(d1, od1);
    const float m2 = fminf(d2, od2);
    const float m3 = fminf(d3, od3);
    d3 = fmaxf(fminf(fmaxf(m1, m2), m3), fminf(m1, m2));
    d2 = t2 ? l1 : wd2;  i2 = t2 ? li1 : wi2;
    d1 = t1 ? od1 : d1;  i1 = t1 ? oi1 : i1;
}

// ---------------------------------------------------------------------------
// Main: 2-pass fp16 MFMA (x_hi*e_hi + x_hi*e_lo) + top-3, LDS double-buffer
// (one barrier per K-step) + register prefetch 2 iterations deep.
// Fragment indexing identical to r3/r4 (verified).
// ---------------------------------------------------------------------------
__global__ __launch_bounds__(256, 2) void mfma_argmin_kernel(
    const _Float16* __restrict__ xhi,
    const _Float16* __restrict__ ehi, const _Float16* __restrict__ elo,
    const float* __restrict__ ce,
    float* __restrict__ pd1, int* __restrict__ pi1,
    float* __restrict__ pd2, int* __restrict__ pi2, float* __restrict__ pd3) {

    __shared__ _Float16 lds[2 * 15360];     // per buffer: A_hi | B_hi | B_lo (128x40 each)

    const int tid  = threadIdx.x;
    const int tileR = blockIdx.x >> 2;
    const int q     = blockIdx.x & 3;
    const int r0    = tileR * 128;
    const int cq    = q * QC;

    const int lane = tid & 63;
    const int w    = tid >> 6;
    const int wr   = w >> 1, wc = w & 1;
    const int n16  = lane & 15, quad = lane >> 4;

    const int srow  = tid >> 1;
    const int shalf = (tid & 1) * 16;
    const int lo0   = srow * 40 + shalf;

    float bd1[16], bd2[16], bd3[16];
    int   bi1[16], bi2[16];
#pragma unroll
    for (int s = 0; s < 16; s++) {
        bd1[s] = 3.4e38f; bd2[s] = 3.4e38f; bd3[s] = 3.4e38f;
        bi1[s] = 0; bi2[s] = 0;
    }

    const float sc = -9.31322574615478515625e-10f;   // -2^-30

    const size_t aBase = (size_t)(r0 + srow) * DD + shalf;
    const size_t bRow  = (size_t)srow * DD + shalf;

    half8 pa0, pa1, pbh0, pbh1, pbl0, pbl1;
    // it=0 load
    pa0 = *(const half8*)(xhi + aBase);
    pa1 = *(const half8*)(xhi + aBase + 8);
    {
        const size_t b = (size_t)cq * DD + bRow;
        pbh0 = *(const half8*)(ehi + b); pbh1 = *(const half8*)(ehi + b + 8);
        pbl0 = *(const half8*)(elo + b); pbl1 = *(const half8*)(elo + b + 8);
    }
    // write buf0
    *(half8*)(lds + lo0) = pa0;              *(half8*)(lds + lo0 + 8) = pa1;
    *(half8*)(lds + 5120 + lo0) = pbh0;      *(half8*)(lds + 5120 + lo0 + 8) = pbh1;
    *(half8*)(lds + 10240 + lo0) = pbl0;     *(half8*)(lds + 10240 + lo0 + 8) = pbl1;
    // it=1 load
    {
        const int nd0 = 32;
        pa0 = *(const half8*)(xhi + aBase + nd0);
        pa1 = *(const half8*)(xhi + aBase + nd0 + 8);
        const size_t b = (size_t)cq * DD + bRow + nd0;
        pbh0 = *(const half8*)(ehi + b); pbh1 = *(const half8*)(ehi + b + 8);
        pbl0 = *(const half8*)(elo + b); pbl1 = *(const half8*)(elo + b + 8);
    }
    __syncthreads();

    float4v acc[4][4];
#pragma unroll
    for (int i = 0; i < 4; i++)
#pragma unroll
        for (int jj = 0; jj < 4; jj++) acc[i][jj] = (float4v){0.f, 0.f, 0.f, 0.f};

    for (int it = 0; it < 256; it++) {
        const _Float16* cb = lds + (it & 1) * 15360;
        // stage it+1 into the other buffer (regs loaded at it-1)
        if (it < 255) {
            _Float16* nb = lds + ((it + 1) & 1) * 15360;
            *(half8*)(nb + lo0) = pa0;          *(half8*)(nb + lo0 + 8) = pa1;
            *(half8*)(nb + 5120 + lo0) = pbh0;  *(half8*)(nb + 5120 + lo0 + 8) = pbh1;
            *(half8*)(nb + 10240 + lo0) = pbl0; *(half8*)(nb + 10240 + lo0 + 8) = pbl1;
        }
        // issue loads for it+2
        if (it < 254) {
            const int nit = it + 2;
            const int nd0 = (nit & 15) * 32;
            pa0 = *(const half8*)(xhi + aBase + nd0);
            pa1 = *(const half8*)(xhi + aBase + nd0 + 8);
            const size_t b = (size_t)(cq + (nit >> 4) * 128) * DD + bRow + nd0;
            pbh0 = *(const half8*)(ehi + b); pbh1 = *(const half8*)(ehi + b + 8);
            pbl0 = *(const half8*)(elo + b); pbl1 = *(const half8*)(elo + b + 8);
        }
        // compute it
        half8 Ah[4];
#pragma unroll
        for (int fm = 0; fm < 4; fm++)
            Ah[fm] = *(const half8*)(cb + (wr * 64 + fm * 16 + n16) * 40 + quad * 8);
#pragma unroll
        for (int fn = 0; fn < 4; fn++) {
            const int off = (wc * 64 + fn * 16 + n16) * 40 + quad * 8;
            const half8 Bh = *(const half8*)(cb + 5120 + off);
            const half8 Bl = *(const half8*)(cb + 10240 + off);
#pragma unroll
            for (int fm = 0; fm < 4; fm++)
                acc[fm][fn] = __builtin_amdgcn_mfma_f32_16x16x32_f16(Ah[fm], Bh, acc[fm][fn], 0, 0, 0);
#pragma unroll
            for (int fm = 0; fm < 4; fm++)
                acc[fm][fn] = __builtin_amdgcn_mfma_f32_16x16x32_f16(Ah[fm], Bl, acc[fm][fn], 0, 0, 0);
        }
        // fold at end of each 128-code tile
        if ((it & 15) == 15) {
            const int c0 = cq + (it >> 4) * 128;
#pragma unroll
            for (int fn = 0; fn < 4; fn++) {
                const int code = c0 + wc * 64 + fn * 16 + n16;
                const float cek = ce[code];
#pragma unroll
                for (int fm = 0; fm < 4; fm++) {
#pragma unroll
                    for (int reg = 0; reg < 4; reg++) {
                        const int s = fm * 4 + reg;
                        const float d = fmaf(sc, acc[fm][fn][reg], cek);
                        const bool lt1 = d < bd1[s];
                        const bool lt2 = d < bd2[s];
                        const bool lt3 = d < bd3[s];
                        bd3[s] = lt2 ? bd2[s] : (lt3 ? d : bd3[s]);
                        bd2[s] = lt1 ? bd1[s] : (lt2 ? d : bd2[s]);
                        bi2[s] = lt1 ? bi1[s] : (lt2 ? code : bi2[s]);
                        bd1[s] = lt1 ? d : bd1[s];
                        bi1[s] = lt1 ? code : bi1[s];
                    }
                }
            }
#pragma unroll
            for (int i = 0; i < 4; i++)
#pragma unroll
                for (int jj = 0; jj < 4; jj++) acc[i][jj] = (float4v){0.f, 0.f, 0.f, 0.f};
        }
        __syncthreads();
    }

    // butterfly merge across 16 col-lanes
#pragma unroll
    for (int s = 0; s < 16; s++) {
#pragma unroll
        for (int off = 1; off < 16; off <<= 1) {
            const float od1 = __shfl_xor(bd1[s], off, 64);
            const int   oi1 = __shfl_xor(bi1[s], off, 64);
            const float od2 = __shfl_xor(bd2[s], off, 64);
            const int   oi2 = __shfl_xor(bi2[s], off, 64);
            const float od3 = __shfl_xor(bd3[s], off, 64);
            merge3(bd1[s], bi1[s], bd2[s], bi2[s], bd3[s], od1, oi1, od2, oi2, od3);
        }
    }

    __syncthreads();
    float* ld1 = (float*)lds;
    int*   li1 = (int*)(lds + 1024 * 1);
    float* ld2 = (float*)(lds + 1024 * 2);
    int*   li2 = (int*)(lds + 1024 * 3);
    float* ld3 = (float*)(lds + 1024 * 4);
    if (n16 == 0) {
#pragma unroll
        for (int fm = 0; fm < 4; fm++)
#pragma unroll
            for (int reg = 0; reg < 4; reg++) {
                const int s = fm * 4 + reg;
                const int rl = wr * 64 + fm * 16 + quad * 4 + reg;
                ld1[wc * 128 + rl] = bd1[s];
                li1[wc * 128 + rl] = bi1[s];
                ld2[wc * 128 + rl] = bd2[s];
                li2[wc * 128 + rl] = bi2[s];
                ld3[wc * 128 + rl] = bd3[s];
            }
    }
    __syncthreads();
    if (tid < 128) {
        float d1 = ld1[tid]; int i1 = li1[tid];
        float d2 = ld2[tid]; int i2 = li2[tid];
        float d3 = ld3[tid];
        merge3(d1, i1, d2, i2, d3,
               ld1[128 + tid], li1[128 + tid], ld2[128 + tid], li2[128 + tid], ld3[128 + tid]);
        const size_t o = (size_t)q * BNR + r0 + tid;
        pd1[o] = d1; pi1[o] = i1; pd2[o] = d2; pi2[o] = i2; pd3[o] = d3;
    }
}

// ---------------------------------------------------------------------------
// Combine + classify. band margin 2.5e-5 (covers 2x worst realistic eps of
// the 2-pass approximation; see round-5 analysis).
// ---------------------------------------------------------------------------
__global__ __launch_bounds__(256) void combine_kernel(
    const float* __restrict__ pd1, const int* __restrict__ pi1,
    const float* __restrict__ pd2, const int* __restrict__ pi2,
    const float* __restrict__ pd3,
    const float* __restrict__ a32, int* __restrict__ codes,
    int* __restrict__ pairlist, int* __restrict__ fulllist,
    unsigned long long* __restrict__ fkey, int* __restrict__ counters) {
    const int r = blockIdx.x * 256 + threadIdx.x;
    float d1 = pd1[r]; int i1 = pi1[r];
    float d2 = pd2[r]; int i2 = pi2[r];
    float d3 = pd3[r];
#pragma unroll
    for (int q = 1; q < NQ; q++) {
        const size_t o = (size_t)q * BNR + r;
        merge3(d1, i1, d2, i2, d3, pd1[o], pi1[o], pd2[o], pi2[o], pd3[o]);
    }
    codes[r] = i1;
    const float ap = a32[r] + 1.0f;
    const int ebits = (int)((__float_as_uint(ap) >> 23) & 255) - 127;
    const float ulpr = __uint_as_float((unsigned)(ebits - 23 + 127) << 23);
    const float band = 2.0f * ulpr + 2.5e-5f;
    if (d2 - d1 <= band) {
        if (d3 - d1 > band) {
            const int p = atomicAdd(&counters[0], 1);
            pairlist[2 * p]     = r;
            pairlist[2 * p + 1] = i1 | (i2 << 13);
        } else {
            const int p = atomicAdd(&counters[1], 1);
            fulllist[p] = r;
            fkey[p] = 0xFFFFFFFFFFFFFFFFULL;
        }
    }
}

// ---------------------------------------------------------------------------
// Pair repair (r4, validated): exact quantized compare of the two candidates.
// ---------------------------------------------------------------------------
__global__ __launch_bounds__(256) void pair_repair_kernel(
    const float* __restrict__ z, const float* __restrict__ embed,
    const float* __restrict__ ce, const float* __restrict__ a32,
    const int* __restrict__ pairlist, const int* __restrict__ counters,
    int* __restrict__ codes) {
    const int p = blockIdx.x * 4 + (threadIdx.x >> 6);
    if (p >= counters[0]) return;
    const int r  = pairlist[2 * p];
    const int pc = pairlist[2 * p + 1];
    const int c1 = pc & 8191, c2 = (pc >> 13) & 8191;
    const int lane = threadIdx.x & 63;
    const float* zr = z + (size_t)r * DD + lane * 8;
    const float* e1 = embed + (size_t)c1 * DD + lane * 8;
    const float* e2 = embed + (size_t)c2 * DD + lane * 8;
    const float4 x0 = *(const float4*)zr,        x1 = *(const float4*)(zr + 4);
    const float4 a0 = *(const float4*)e1,        a1 = *(const float4*)(e1 + 4);
    const float4 b0 = *(const float4*)e2,        b1 = *(const float4*)(e2 + 4);
    float s1 = x0.x*a0.x + x0.y*a0.y + x0.z*a0.z + x0.w*a0.w
             + x1.x*a1.x + x1.y*a1.y + x1.z*a1.z + x1.w*a1.w;
    float s2 = x0.x*b0.x + x0.y*b0.y + x0.z*b0.z + x0.w*b0.w
             + x1.x*b1.x + x1.y*b1.y + x1.z*b1.z + x1.w*b1.w;
#pragma unroll
    for (int off = 32; off > 0; off >>= 1) {
        s1 += __shfl_down(s1, off, 64);
        s2 += __shfl_down(s2, off, 64);
    }
    if (lane == 0) {
        const float ar = a32[r];
        const float dq1 = __fadd_rn(__fsub_rn(ar, __fmul_rn(2.0f, s1)), ce[c1]);
        const float dq2 = __fadd_rn(__fsub_rn(ar, __fmul_rn(2.0f, s2)), ce[c2]);
        const bool t = (dq2 < dq1) || (dq2 == dq1 && c2 < c1);
        codes[r] = t ? c2 : c1;
    }
}

// ---------------------------------------------------------------------------
// Full repair (r4, validated): row x code-chunk parallel, atomicMin u64 keys.
// ---------------------------------------------------------------------------
__global__ __launch_bounds__(256) void full_repair_kernel(
    const float* __restrict__ z, const float* __restrict__ embed,
    const float* __restrict__ ce, const float* __restrict__ a32,
    const int* __restrict__ fulllist, const int* __restrict__ counters,
    unsigned long long* __restrict__ fkey) {
    const int nf = counters[1];
    const int chunk = blockIdx.x & 7;
    const int lane = threadIdx.x & 63;
    const int wv = threadIdx.x >> 6;
    __shared__ float xs[512];
    for (int slot = blockIdx.x >> 3; slot < nf; slot += 2048) {
        const int r = fulllist[slot];
        __syncthreads();
        if (threadIdx.x < 128)
            ((float4*)xs)[threadIdx.x] = ((const float4*)(z + (size_t)r * DD))[threadIdx.x];
        __syncthreads();
        float x[8];
        *(float4*)&x[0] = ((float4*)xs)[lane * 2];
        *(float4*)&x[4] = ((float4*)xs)[lane * 2 + 1];
        const float ar = a32[r];
        float bd = 3.4e38f; int bc = 0x7fffffff;
        const int cbase = chunk * 1024 + wv * 256;
        for (int cc = 0; cc < 256; cc++) {
            const int c = cbase + cc;
            const float* er = embed + (size_t)c * DD + lane * 8;
            const float4 e0 = *(const float4*)er, e1 = *(const float4*)(er + 4);
            float s = x[0]*e0.x + x[1]*e0.y + x[2]*e0.z + x[3]*e0.w
                    + x[4]*e1.x + x[5]*e1.y + x[6]*e1.z + x[7]*e1.w;
#pragma unroll
            for (int off = 32; off > 0; off >>= 1) s += __shfl_down(s, off, 64);
            s = __shfl(s, 0, 64);
            const float dq = __fadd_rn(__fsub_rn(ar, __fmul_rn(2.0f, s)), ce[c]);
            if (dq < bd || (dq == bd && c < bc)) { bd = dq; bc = c; }
        }
        if (lane == 0) {
            unsigned int fb = __float_as_uint(bd);
            fb = (fb & 0x80000000u) ? ~fb : (fb | 0x80000000u);
            const unsigned long long key = ((unsigned long long)fb << 32) | (unsigned)bc;
            atomicMin(&fkey[slot], key);
        }
    }
}

__global__ __launch_bounds__(256) void full_combine_kernel(
    const unsigned long long* __restrict__ fkey, const int* __restrict__ fulllist,
    const int* __restrict__ counters, int* __restrict__ codes) {
    const int nf = counters[1];
    for (int p = blockIdx.x * 256 + threadIdx.x; p < nf; p += 32768)
        codes[fulllist[p]] = (int)(fkey[p] & 0xFFFFFFFFULL);
}

// ---------------------------------------------------------------------------
// Epilogue
// ---------------------------------------------------------------------------
__global__ __launch_bounds__(128) void gather_loss_kernel(
    const float* __restrict__ z, const float* __restrict__ embed,
    const int* __restrict__ codes,
    float* __restrict__ out_zq, float* __restrict__ out_codes,
    float* __restrict__ partial) {
    const int r = blockIdx.x;
    const int t = threadIdx.x;
    const int c = codes[r];
    const float4 zv = *(const float4*)(z + (size_t)r * DD + t * 4);
    const float4 ev = *(const float4*)(embed + (size_t)c * DD + t * 4);
    *(float4*)(out_zq + (size_t)r * DD + t * 4) = ev;
    const float dx = zv.x - ev.x, dy = zv.y - ev.y;
    const float dz2 = zv.z - ev.z, dw = zv.w - ev.w;
    float s = dx*dx + dy*dy + dz2*dz2 + dw*dw;
#pragma unroll
    for (int off = 32; off > 0; off >>= 1) s += __shfl_down(s, off, 64);
    __shared__ float wsum[2];
    if ((t & 63) == 0) wsum[t >> 6] = s;
    __syncthreads();
    if (t == 0) {
        partial[r] = wsum[0] + wsum[1];
        out_codes[r] = (float)c;
    }
}

__global__ __launch_bounds__(256) void loss_reduce_kernel(
    const float* __restrict__ partial, float* __restrict__ out_loss) {
    const int t = threadIdx.x;
    double s = 0.0;
    for (int i = t; i < BNR; i += 256) s += (double)partial[i];
    __shared__ double sd[256];
    sd[t] = s;
    __syncthreads();
    for (int k = 128; k > 0; k >>= 1) {
        if (t < k) sd[t] += sd[t + k];
        __syncthreads();
    }
    if (t == 0) out_loss[0] = (float)(0.1 * sd[0] / (double)((size_t)BNR * DD));
}

// ---------------------------------------------------------------------------
extern "C" void kernel_launch(void* const* d_in, const int* in_sizes, int n_in,
                              void* d_out, int out_size, void* d_ws, size_t ws_size,
                              hipStream_t stream) {
    const float* z     = (const float*)d_in[0];
    const float* embed = (const float*)d_in[1];
    float* out = (float*)d_out;
    float* out_zq    = out;
    float* out_codes = out + (size_t)BNR * DD;
    float* out_loss  = out + (size_t)BNR * DD + BNR;

    // z hi-split lives in the z_q output region (32 MB; overwritten at the end).
    _Float16* xhi = (_Float16*)d_out;

    char* ws = (char*)d_ws;
    int*   counters = (int*)  (ws + 0);
    float* ce       = (float*)(ws + 256);
    float* a32      = (float*)(ws + 33024);
    float* pd1      = (float*)(ws + 164096);
    int*   pi1      = (int*)  (ws + 688384);
    float* pd2      = (float*)(ws + 1212672);
    int*   pi2      = (int*)  (ws + 1736960);
    float* pd3      = (float*)(ws + 2261248);
    int*   codes    = (int*)  (ws + 2785536);
    int*   pairlist = (int*)  (ws + 2916608);
    int*   fulllist = (int*)  (ws + 3178752);
    unsigned long long* fkey = (unsigned long long*)(ws + 3309824);
    _Float16* ehi   = (_Float16*)(ws + 3571968);
    _Float16* elo   = (_Float16*)(ws + 11960576);
    float* partial  = pd1;                       // pd1 dead after combine

    split_hi_kernel<<<dim3(BNR * DD / 2048), dim3(256), 0, stream>>>(z, xhi, 2048.0f, counters);
    split_hilo_kernel<<<dim3(KC * DD / 2048), dim3(256), 0, stream>>>(embed, ehi, elo, 1048576.0f);
    rowsq_wave_kernel<<<dim3(BNR / 4), dim3(256), 0, stream>>>(z, a32, BNR);
    rowsq_wave_kernel<<<dim3(KC / 4), dim3(256), 0, stream>>>(embed, ce, KC);
    mfma_argmin_kernel<<<dim3((BNR / 128) * NQ), dim3(256), 0, stream>>>(
        xhi, ehi, elo, ce, pd1, pi1, pd2, pi2, pd3);
    combine_kernel<<<dim3(BNR / 256), dim3(256), 0, stream>>>(
        pd1, pi1, pd2, pi2, pd3, a32, codes, pairlist, fulllist, fkey, counters);
    pair_repair_kernel<<<dim3(8192), dim3(256), 0, stream>>>(
        z, embed, ce, a32, pairlist, counters, codes);
    full_repair_kernel<<<dim3(16384), dim3(256), 0, stream>>>(
        z, embed, ce, a32, fulllist, counters, fkey);
    full_combine_kernel<<<dim3(128), dim3(256), 0, stream>>>(
        fkey, fulllist, counters, codes);
    gather_loss_kernel<<<dim3(BNR), dim3(128), 0, stream>>>(
        z, embed, codes, out_zq, out_codes, partial);
    loss_reduce_kernel<<<dim3(1), dim3(256), 0, stream>>>(partial, out_loss);
}